// Round 1
// baseline (43.825 us; speedup 1.0000x reference)
//
#include <hip/hip_runtime.h>
#include <hip/hip_bf16.h>

#define SEQ 2048
#define HID 2048
#define NB  8
#define WMAX 30
#define EPSF 1e-8f

// ---------------- Kernel 1: per-row dot1, dot2, nsq ----------------
// 512 threads = 8 waves, 1 row per wave. Grid = NB * SEQ / 8 = 2048 blocks.
__global__ __launch_bounds__(512)
void k1_dots(const float* __restrict__ seq, const int* __restrict__ idxs,
             float* __restrict__ ws) {
    __shared__ float4 q1s[HID / 4];
    __shared__ float4 q2s[HID / 4];

    int bid = blockIdx.x;
    int b = bid >> 8;                 // SEQ/8 = 256 blocks per example
    int rbase = (bid & 255) * 8;
    int t = threadIdx.x;

    int sep0 = idxs[2 * b];

    const float4* q1p = (const float4*)(seq + ((size_t)b * SEQ + 1) * HID);
    const float4* q2p = (const float4*)(seq + ((size_t)b * SEQ + (sep0 - 1)) * HID);
    q1s[t] = q1p[t];                  // 512 threads x 1 float4 = 2048 floats
    q2s[t] = q2p[t];
    __syncthreads();

    int w = t >> 6, lane = t & 63;
    int i = rbase + w;
    const float4* rp = (const float4*)(seq + ((size_t)b * SEQ + i) * HID);

    float s1 = 0.f, s2 = 0.f, s3 = 0.f;
#pragma unroll
    for (int k = 0; k < 8; ++k) {
        float4 v  = rp[k * 64 + lane];
        float4 a  = q1s[k * 64 + lane];
        float4 bq = q2s[k * 64 + lane];
        s1 += v.x * a.x  + v.y * a.y  + v.z * a.z  + v.w * a.w;
        s2 += v.x * bq.x + v.y * bq.y + v.z * bq.z + v.w * bq.w;
        s3 += v.x * v.x  + v.y * v.y  + v.z * v.z  + v.w * v.w;
    }
#pragma unroll
    for (int off = 32; off; off >>= 1) {
        s1 += __shfl_xor(s1, off);
        s2 += __shfl_xor(s2, off);
        s3 += __shfl_xor(s3, off);
    }
    if (lane == 0) {
        size_t o = (size_t)b * SEQ + i;
        ws[o] = s1;
        ws[(size_t)NB * SEQ + o] = s2;
        ws[2 * (size_t)NB * SEQ + o] = s3;
    }
}

// order-preserving uint encoding of float (no NaNs present)
__device__ __forceinline__ unsigned enc_f(float f) {
    unsigned u = __float_as_uint(f);
    return (u & 0x80000000u) ? ~u : (u | 0x80000000u);
}
__device__ __forceinline__ float dec_f(unsigned k) {
    unsigned u = (k & 0x80000000u) ? (k ^ 0x80000000u) : ~k;
    return __uint_as_float(u);
}

// ---------------- Kernel 2: banded argmax + scatter-max + stats ----------------
// One block per example, 1024 threads, 2 rows per thread.
__global__ __launch_bounds__(1024)
void k2_band(const float* __restrict__ ws, const int* __restrict__ idxs,
             float* __restrict__ out) {
    __shared__ float dot2_s[SEQ];
    __shared__ float nsq_s[SEQ];
    __shared__ unsigned endv_s[SEQ];
    __shared__ float red[5][16];

    int b = blockIdx.x;
    int t = threadIdx.x;
    int sep0 = idxs[2 * b], sep1 = idxs[2 * b + 1];

    const float* dot1 = ws + (size_t)b * SEQ;
    const float* dot2 = ws + (size_t)NB * SEQ + (size_t)b * SEQ;
    const float* nsq  = ws + 2 * (size_t)NB * SEQ + (size_t)b * SEQ;

    const unsigned ENC_NEGINF = 0x007fffffu;  // enc(-inf)

#pragma unroll
    for (int r = 0; r < 2; ++r) {
        int i = t + r * 1024;
        dot2_s[i] = dot2[i];
        nsq_s[i]  = nsq[i];
        endv_s[i] = ENC_NEGINF;
    }
    __syncthreads();

    float qn = sqrtf(nsq_s[1] + nsq_s[sep0 - 1]);
    float dq = fmaxf(qn, EPSF);

    float slog[2];
#pragma unroll
    for (int r = 0; r < 2; ++r) {
        int i = t + r * 1024;
        bool range_ok = (i >= sep0 + 1) && (i < sep1);
        float best = -__builtin_inff();
        int arg = 0;
        bool any = false;
        float d1 = dot1[i];
        float ni = nsq_s[i];
        for (int d = 0; d < WMAX; ++d) {
            int jraw = i + d;
            if (range_ok && jraw < sep1) {
                float num = d1 + dot2_s[jraw];
                float den = fmaxf(sqrtf(ni + nsq_s[jraw]), EPSF) * dq;
                float sim = num / den;
                if (sim > best) { best = sim; arg = d; }
                any = true;
            }
        }
        slog[r] = any ? best : 0.0f;
        if (any) {
            int e = i + arg;
            if (e > SEQ - 1) e = SEQ - 1;
            atomicMax(&endv_s[e], enc_f(best));
        }
    }
    __syncthreads();

    float elog[2];
#pragma unroll
    for (int r = 0; r < 2; ++r) {
        int i = t + r * 1024;
        unsigned k = endv_s[i];
        elog[r] = (k == ENC_NEGINF) ? 0.0f : dec_f(k);
    }

    // block stats: sum, sumsq for start/end, max of start
    float ssum = 0.f, ssq = 0.f, esum = 0.f, esq = 0.f, smax = -__builtin_inff();
#pragma unroll
    for (int r = 0; r < 2; ++r) {
        ssum += slog[r]; ssq += slog[r] * slog[r];
        esum += elog[r]; esq += elog[r] * elog[r];
        smax = fmaxf(smax, slog[r]);
    }
#pragma unroll
    for (int off = 32; off; off >>= 1) {
        ssum += __shfl_xor(ssum, off);
        ssq  += __shfl_xor(ssq,  off);
        esum += __shfl_xor(esum, off);
        esq  += __shfl_xor(esq,  off);
        smax = fmaxf(smax, __shfl_xor(smax, off));
    }
    int lane = t & 63, w = t >> 6;
    if (lane == 0) {
        red[0][w] = ssum; red[1][w] = ssq; red[2][w] = esum;
        red[3][w] = esq;  red[4][w] = smax;
    }
    __syncthreads();

    float S0 = 0.f, S1 = 0.f, E0 = 0.f, E1 = 0.f, MX = -__builtin_inff();
    for (int k = 0; k < 16; ++k) {
        S0 += red[0][k]; S1 += red[1][k]; E0 += red[2][k];
        E1 += red[3][k]; MX = fmaxf(MX, red[4][k]);
    }
    float ms = S0 / SEQ;
    float ss = sqrtf(fmaxf(S1 - SEQ * ms * ms, 0.f) / (SEQ - 1));
    float me = E0 / SEQ;
    float se = sqrtf(fmaxf(E1 - SEQ * me * me, 0.f) / (SEQ - 1));
    bool flip = (MX < ms + ss) || (MX < me + se);

#pragma unroll
    for (int r = 0; r < 2; ++r) {
        int i = t + r * 1024;
        float so = slog[r], eo = elog[r];
        if (flip) {
            so = (so == 0.f) ? -0.001f : -so;
            eo = (eo == 0.f) ? -0.001f : -eo;
        }
        out[(size_t)b * SEQ + i] = so;
        out[(size_t)NB * SEQ + (size_t)b * SEQ + i] = eo;
    }
}

extern "C" void kernel_launch(void* const* d_in, const int* in_sizes, int n_in,
                              void* d_out, int out_size, void* d_ws, size_t ws_size,
                              hipStream_t stream) {
    const float* seq = (const float*)d_in[0];
    const int* idxs = (const int*)d_in[1];
    float* out = (float*)d_out;
    float* ws = (float*)d_ws;

    k1_dots<<<NB * SEQ / 8, 512, 0, stream>>>(seq, idxs, ws);
    k2_band<<<NB, 1024, 0, stream>>>(ws, idxs, out);
}

// Round 2
// 36.244 us; speedup vs baseline: 1.2092x; 1.2092x over previous
//
#include <hip/hip_runtime.h>
#include <hip/hip_bf16.h>

#define SEQ 2048
#define HID 2048
#define NB  8
#define WMAX 30
#define WIN 288            // 256 rows + 32 window tail
#define EPSF 1e-8f
#define ENC_NEGINF 0x007fffffu

// ws layout (floats): [0] dot1 | [1] dot2 | [2] nsq | [3] slog | [4] endv(uint)
// each segment NB*SEQ elements.

// ---------------- Kernel 1: per-row dot1, dot2, nsq (+ endv init) ----------------
// 512 threads = 8 waves, 1 row per wave. Grid = NB * SEQ / 8 = 2048 blocks.
__global__ __launch_bounds__(512)
void k1_dots(const float* __restrict__ seq, const int* __restrict__ idxs,
             float* __restrict__ ws) {
    __shared__ float4 q1s[HID / 4];
    __shared__ float4 q2s[HID / 4];

    int bid = blockIdx.x;
    int b = bid >> 8;                 // SEQ/8 = 256 blocks per example
    int rbase = (bid & 255) * 8;
    int t = threadIdx.x;

    int sep0 = idxs[2 * b];

    const float4* q1p = (const float4*)(seq + ((size_t)b * SEQ + 1) * HID);
    const float4* q2p = (const float4*)(seq + ((size_t)b * SEQ + (sep0 - 1)) * HID);
    q1s[t] = q1p[t];
    q2s[t] = q2p[t];
    __syncthreads();

    int w = t >> 6, lane = t & 63;
    int i = rbase + w;
    const float4* rp = (const float4*)(seq + ((size_t)b * SEQ + i) * HID);

    float s1 = 0.f, s2 = 0.f, s3 = 0.f;
#pragma unroll
    for (int k = 0; k < 8; ++k) {
        float4 v  = rp[k * 64 + lane];
        float4 a  = q1s[k * 64 + lane];
        float4 bq = q2s[k * 64 + lane];
        s1 += v.x * a.x  + v.y * a.y  + v.z * a.z  + v.w * a.w;
        s2 += v.x * bq.x + v.y * bq.y + v.z * bq.z + v.w * bq.w;
        s3 += v.x * v.x  + v.y * v.y  + v.z * v.z  + v.w * v.w;
    }
#pragma unroll
    for (int off = 32; off; off >>= 1) {
        s1 += __shfl_xor(s1, off);
        s2 += __shfl_xor(s2, off);
        s3 += __shfl_xor(s3, off);
    }
    if (lane == 0) {
        size_t o = (size_t)b * SEQ + i;
        ws[o] = s1;
        ws[(size_t)NB * SEQ + o] = s2;
        ws[2 * (size_t)NB * SEQ + o] = s3;
        ((unsigned*)(ws + 4 * (size_t)NB * SEQ))[o] = ENC_NEGINF;  // scatter-max init
    }
}

// order-preserving uint encoding of float (no NaNs present)
__device__ __forceinline__ unsigned enc_f(float f) {
    unsigned u = __float_as_uint(f);
    return (u & 0x80000000u) ? ~u : (u | 0x80000000u);
}
__device__ __forceinline__ float dec_f(unsigned k) {
    unsigned u = (k & 0x80000000u) ? (k ^ 0x80000000u) : ~k;
    return __uint_as_float(u);
}

// ---------------- Kernel 2a: banded argmax + global scatter-max ----------------
// Grid = NB*8 blocks, 256 threads; block handles 256 consecutive rows.
__global__ __launch_bounds__(256)
void k2a_band(const float* __restrict__ ws, const int* __restrict__ idxs) {
    __shared__ float d2s[WIN];
    __shared__ float nss[WIN];

    int blk = blockIdx.x;
    int b = blk >> 3;
    int base = (blk & 7) * 256;
    int t = threadIdx.x;

    const float* dot1 = ws + (size_t)b * SEQ;
    const float* dot2 = ws + (size_t)NB * SEQ + (size_t)b * SEQ;
    const float* nsq  = ws + 2 * (size_t)NB * SEQ + (size_t)b * SEQ;
    float* slog       = (float*)(ws + 3 * (size_t)NB * SEQ) + (size_t)b * SEQ;
    unsigned* endv    = (unsigned*)(ws + 4 * (size_t)NB * SEQ) + (size_t)b * SEQ;

    int g0 = base + t;
    d2s[t] = dot2[g0];
    nss[t] = nsq[g0];
    if (t < WIN - 256) {
        int g1 = base + 256 + t;
        int gc = g1 > SEQ - 1 ? SEQ - 1 : g1;
        d2s[256 + t] = dot2[gc];
        nss[256 + t] = nsq[gc];
    }
    __syncthreads();

    int sep0 = idxs[2 * b], sep1 = idxs[2 * b + 1];
    float qn = sqrtf(nsq[1] + nsq[sep0 - 1]);
    float invq = 1.0f / fmaxf(qn, EPSF);

    int i = base + t;
    bool range_ok = (i >= sep0 + 1) && (i < sep1);
    float d1 = dot1[i];
    float ni = nss[t];

    float best = -__builtin_inff();
    int arg = 0;
    bool any = false;
#pragma unroll
    for (int d = 0; d < WMAX; ++d) {
        int jraw = i + d;
        if (range_ok && jraw < sep1) {
            float num = d1 + d2s[t + d];
            float sim = num * rsqrtf(ni + nss[t + d]) * invq;
            if (sim > best) { best = sim; arg = d; }
            any = true;
        }
    }
    slog[i] = any ? best : 0.0f;
    if (any) {
        int e = i + arg;
        if (e > SEQ - 1) e = SEQ - 1;
        atomicMax(&endv[e], enc_f(best));
    }
}

// ---------------- Kernel 2b: stats + flip + output ----------------
// Grid = NB blocks, 1024 threads, 2 rows per thread.
__global__ __launch_bounds__(1024)
void k2b_fin(const float* __restrict__ ws, float* __restrict__ out) {
    __shared__ float red[5][16];

    int b = blockIdx.x;
    int t = threadIdx.x;

    const float* slogp  = (const float*)(ws + 3 * (size_t)NB * SEQ) + (size_t)b * SEQ;
    const unsigned* ev  = (const unsigned*)(ws + 4 * (size_t)NB * SEQ) + (size_t)b * SEQ;

    float slog[2], elog[2];
#pragma unroll
    for (int r = 0; r < 2; ++r) {
        int i = t + r * 1024;
        slog[r] = slogp[i];
        unsigned k = ev[i];
        elog[r] = (k == ENC_NEGINF) ? 0.0f : dec_f(k);
    }

    float ssum = 0.f, ssq = 0.f, esum = 0.f, esq = 0.f, smax = -__builtin_inff();
#pragma unroll
    for (int r = 0; r < 2; ++r) {
        ssum += slog[r]; ssq += slog[r] * slog[r];
        esum += elog[r]; esq += elog[r] * elog[r];
        smax = fmaxf(smax, slog[r]);
    }
#pragma unroll
    for (int off = 32; off; off >>= 1) {
        ssum += __shfl_xor(ssum, off);
        ssq  += __shfl_xor(ssq,  off);
        esum += __shfl_xor(esum, off);
        esq  += __shfl_xor(esq,  off);
        smax = fmaxf(smax, __shfl_xor(smax, off));
    }
    int lane = t & 63, w = t >> 6;
    if (lane == 0) {
        red[0][w] = ssum; red[1][w] = ssq; red[2][w] = esum;
        red[3][w] = esq;  red[4][w] = smax;
    }
    __syncthreads();

    float S0 = 0.f, S1 = 0.f, E0 = 0.f, E1 = 0.f, MX = -__builtin_inff();
    for (int k = 0; k < 16; ++k) {
        S0 += red[0][k]; S1 += red[1][k]; E0 += red[2][k];
        E1 += red[3][k]; MX = fmaxf(MX, red[4][k]);
    }
    float ms = S0 / SEQ;
    float ss = sqrtf(fmaxf(S1 - SEQ * ms * ms, 0.f) / (SEQ - 1));
    float me = E0 / SEQ;
    float se = sqrtf(fmaxf(E1 - SEQ * me * me, 0.f) / (SEQ - 1));
    bool flip = (MX < ms + ss) || (MX < me + se);

#pragma unroll
    for (int r = 0; r < 2; ++r) {
        int i = t + r * 1024;
        float so = slog[r], eo = elog[r];
        if (flip) {
            so = (so == 0.f) ? -0.001f : -so;
            eo = (eo == 0.f) ? -0.001f : -eo;
        }
        out[(size_t)b * SEQ + i] = so;
        out[(size_t)NB * SEQ + (size_t)b * SEQ + i] = eo;
    }
}

extern "C" void kernel_launch(void* const* d_in, const int* in_sizes, int n_in,
                              void* d_out, int out_size, void* d_ws, size_t ws_size,
                              hipStream_t stream) {
    const float* seq = (const float*)d_in[0];
    const int* idxs = (const int*)d_in[1];
    float* out = (float*)d_out;
    float* ws = (float*)d_ws;

    k1_dots<<<NB * SEQ / 8, 512, 0, stream>>>(seq, idxs, ws);
    k2a_band<<<NB * 8, 256, 0, stream>>>(ws, idxs);
    k2b_fin<<<NB, 1024, 0, stream>>>(ws, out);
}